// Round 1
// baseline (1521.494 us; speedup 1.0000x reference)
//
#include <hip/hip_runtime.h>

#define IN_DIM 512
#define HIDC   256
#define TEMP_INV 2.0f

typedef __bf16 bf16x8 __attribute__((ext_vector_type(8)));
typedef float  f32x4  __attribute__((ext_vector_type(4)));

__device__ __forceinline__ unsigned short f32_to_bf16(float f) {
  union { float f; unsigned int u; } v; v.f = f;
  unsigned int u = v.u;
  u += 0x7FFFu + ((u >> 16) & 1u);
  return (unsigned short)(u >> 16);
}

// ---------------- degree / norm ----------------
__global__ void deg_count_kernel(const int* __restrict__ src, const int* __restrict__ dst,
                                 float* __restrict__ out_deg, float* __restrict__ in_deg, int E) {
  int e = blockIdx.x * blockDim.x + threadIdx.x;
  if (e < E) {
    atomicAdd(&out_deg[src[e]], 1.0f);
    atomicAdd(&in_deg[dst[e]], 1.0f);
  }
}

__global__ void make_norm_kernel(const float* __restrict__ out_deg, const float* __restrict__ in_deg,
                                 float* __restrict__ src_norm, float* __restrict__ dst_norm, int N) {
  int n = blockIdx.x * blockDim.x + threadIdx.x;
  if (n < N) {
    float od = out_deg[n], id = in_deg[n];
    src_norm[n] = od > 0.f ? 1.0f / sqrtf(od) : 0.f;
    dst_norm[n] = id > 0.f ? 1.0f / sqrtf(id) : 0.f;
  }
}

// ---------------- fp32 tiled GEMM: Y[M,256] = X[M,K] @ W[K,256] ----------------
__global__ __launch_bounds__(256) void gemm_f32(const float* __restrict__ X,
                                                const float* __restrict__ W,
                                                float* __restrict__ Y, int M, int K) {
  __shared__ float As[16][64 + 1];
  __shared__ float Bs[16][64 + 1];
  const int tx = threadIdx.x, ty = threadIdx.y;
  const int t = ty * 16 + tx;
  const int m0 = blockIdx.x * 64;
  const int n0 = blockIdx.y * 64;
  float acc[4][4] = {};
  for (int k0 = 0; k0 < K; k0 += 16) {
#pragma unroll
    for (int i = 0; i < 4; ++i) {
      int idx = t + i * 256;
      int m = idx >> 4, k = idx & 15;
      As[k][m] = X[(size_t)(m0 + m) * K + k0 + k];
    }
#pragma unroll
    for (int i = 0; i < 4; ++i) {
      int idx = t + i * 256;
      int n = idx & 63, k = idx >> 6;
      Bs[k][n] = W[(size_t)(k0 + k) * HIDC + n0 + n];
    }
    __syncthreads();
#pragma unroll
    for (int k = 0; k < 16; ++k) {
      float a[4], b[4];
#pragma unroll
      for (int i = 0; i < 4; ++i) a[i] = As[k][ty * 4 + i];
#pragma unroll
      for (int j = 0; j < 4; ++j) b[j] = Bs[k][tx * 4 + j];
#pragma unroll
      for (int i = 0; i < 4; ++i)
#pragma unroll
        for (int j = 0; j < 4; ++j) acc[i][j] += a[i] * b[j];
    }
    __syncthreads();
  }
#pragma unroll
  for (int i = 0; i < 4; ++i)
#pragma unroll
    for (int j = 0; j < 4; ++j)
      Y[(size_t)(m0 + ty * 4 + i) * HIDC + n0 + tx * 4 + j] = acc[i][j];
}

// ---------------- edge scatter: agg[dst] += x[src] * src_norm[src] ----------------
__global__ void scatter_kernel(const float* __restrict__ x, const float* __restrict__ src_norm,
                               const int* __restrict__ src, const int* __restrict__ dst,
                               float* __restrict__ agg) {
  int e = blockIdx.x;
  int c = threadIdx.x;
  int s = src[e], d = dst[e];
  float v = x[(size_t)s * HIDC + c] * src_norm[s];
  atomicAdd(&agg[(size_t)d * HIDC + c], v);
}

// ---------------- out = dst_norm * agg + b [, relu] ----------------
__global__ void post_agg_kernel(const float* __restrict__ agg, const float* __restrict__ dst_norm,
                                const float* __restrict__ bias, float* __restrict__ out,
                                int total, int do_relu) {
  int idx = blockIdx.x * blockDim.x + threadIdx.x;
  if (idx < total) {
    int n = idx >> 8, c = idx & 255;
    float v = dst_norm[n] * agg[idx] + bias[c];
    if (do_relu) v = fmaxf(v, 0.f);
    out[idx] = v;
  }
}

// ---------------- out = l2norm(in + bias) ; one block per node ----------------
__global__ __launch_bounds__(256) void l2norm_kernel(const float* __restrict__ in,
                                                     const float* __restrict__ bias,
                                                     float* __restrict__ out) {
  int n = blockIdx.x;
  int c = threadIdx.x;
  float v = in[(size_t)n * HIDC + c] + (bias ? bias[c] : 0.f);
  float s = v * v;
#pragma unroll
  for (int m = 1; m < 64; m <<= 1) s += __shfl_xor(s, m, 64);
  __shared__ float red[4];
  if ((threadIdx.x & 63) == 0) red[threadIdx.x >> 6] = s;
  __syncthreads();
  float tot = red[0] + red[1] + red[2] + red[3];
  float nn = sqrtf(tot);
  out[(size_t)n * HIDC + c] = v / fmaxf(nn, 1e-12f);
}

__global__ void to_bf16_kernel(const float* __restrict__ in, unsigned short* __restrict__ out, int count) {
  int i = blockIdx.x * blockDim.x + threadIdx.x;
  if (i < count) out[i] = f32_to_bf16(in[i]);
}

// ---------------- neg_sim[i] = sum_j exp(z_i . z_j / T) via bf16 MFMA ----------------
__global__ __launch_bounds__(256) void negsim_kernel(const unsigned short* __restrict__ zb,
                                                     float* __restrict__ neg_sim,
                                                     int jlen) {
  const int lane = threadIdx.x & 63;
  const int wave = threadIdx.x >> 6;
  const int i0 = blockIdx.x * 64 + wave * 16;
  const int jbase = blockIdx.y * jlen;

  // A-frag: lane l holds z[i0 + (l&15)][ (l>>4)*8 + 32*kk .. +8 ]
  const unsigned short* arow = zb + (size_t)(i0 + (lane & 15)) * HIDC + ((lane >> 4) * 8);
  bf16x8 afrag[8];
#pragma unroll
  for (int kk = 0; kk < 8; ++kk) afrag[kk] = *(const bf16x8*)(arow + kk * 32);

  float rowsum[4] = {0.f, 0.f, 0.f, 0.f};
  for (int jt = 0; jt < jlen; jt += 16) {
    const unsigned short* brow = zb + (size_t)(jbase + jt + (lane & 15)) * HIDC + ((lane >> 4) * 8);
    f32x4 acc = {0.f, 0.f, 0.f, 0.f};
#pragma unroll
    for (int kk = 0; kk < 8; ++kk) {
      bf16x8 bfrag = *(const bf16x8*)(brow + kk * 32);
      acc = __builtin_amdgcn_mfma_f32_16x16x32_bf16(afrag[kk], bfrag, acc, 0, 0, 0);
    }
    // D mapping: col = lane&15, row = (lane>>4)*4 + r  [m89-verified]
#pragma unroll
    for (int r = 0; r < 4; ++r) rowsum[r] += __expf(acc[r] * TEMP_INV);
  }
  // reduce the 16 columns held across lanes (same lane>>4 group)
#pragma unroll
  for (int m = 1; m < 16; m <<= 1)
#pragma unroll
    for (int r = 0; r < 4; ++r) rowsum[r] += __shfl_xor(rowsum[r], m, 64);
  if ((lane & 15) == 0) {
    int g = lane >> 4;
#pragma unroll
    for (int r = 0; r < 4; ++r) atomicAdd(&neg_sim[i0 + g * 4 + r], rowsum[r]);
  }
}

// ---------------- sim[e] = <un[src], q[dst]> / T ; one wave per edge ----------------
__global__ __launch_bounds__(256) void edge_sim_kernel(const float* __restrict__ un,
                                                       const float* __restrict__ q,
                                                       const int* __restrict__ src,
                                                       const int* __restrict__ dst,
                                                       float* __restrict__ sim, int E) {
  int e = blockIdx.x * 4 + (threadIdx.x >> 6);
  if (e >= E) return;
  int lane = threadIdx.x & 63;
  int s = src[e], d = dst[e];
  float4 a = *(const float4*)(un + (size_t)s * HIDC + lane * 4);
  float4 b = *(const float4*)(q + (size_t)d * HIDC + lane * 4);
  float dotv = a.x * b.x + a.y * b.y + a.z * b.z + a.w * b.w;
#pragma unroll
  for (int m = 1; m < 64; m <<= 1) dotv += __shfl_xor(dotv, m, 64);
  if (lane == 0) sim[e] = dotv * TEMP_INV;
}

// ---------------- per-edge scores scattered into pos/neg sums ----------------
__global__ void edge_scores_kernel(const float* __restrict__ sim, const int* __restrict__ dst,
                                   const float* __restrict__ neg_sim,
                                   float* __restrict__ pos_sum, float* __restrict__ neg_sum, int E) {
  int e = blockIdx.x * blockDim.x + threadIdx.x;
  if (e < E) {
    int d = dst[e];
    float s = sim[e];
    atomicAdd(&pos_sum[d], s);
    float m = __logf(neg_sim[d] + __expf(s));
    atomicAdd(&neg_sum[d], m);
  }
}

// ---------------- final mean ----------------
__global__ __launch_bounds__(256) void finalize_kernel(const float* __restrict__ pos_sum,
                                                       const float* __restrict__ neg_sum,
                                                       const float* __restrict__ in_deg,
                                                       float* __restrict__ out, int N) {
  float acc = 0.f;
  for (int n = threadIdx.x; n < N; n += 256) {
    float d = in_deg[n];
    if (d > 0.f) acc += (neg_sum[n] - pos_sum[n]) / fmaxf(d, 1.0f);
  }
#pragma unroll
  for (int m = 1; m < 64; m <<= 1) acc += __shfl_xor(acc, m, 64);
  __shared__ float red[4];
  if ((threadIdx.x & 63) == 0) red[threadIdx.x >> 6] = acc;
  __syncthreads();
  if (threadIdx.x == 0) out[0] = (red[0] + red[1] + red[2] + red[3]) / (float)N;
}

extern "C" void kernel_launch(void* const* d_in, const int* in_sizes, int n_in,
                              void* d_out, int out_size, void* d_ws, size_t ws_size,
                              hipStream_t stream) {
  const float* feat = (const float*)d_in[0];
  const int* src = (const int*)d_in[1];
  const int* dst = (const int*)d_in[2];
  const float* W1 = (const float*)d_in[3];
  const float* b1 = (const float*)d_in[4];
  const float* W2 = (const float*)d_in[5];
  const float* b2 = (const float*)d_in[6];
  const float* Wt1 = (const float*)d_in[7];
  const float* bt1 = (const float*)d_in[8];
  const float* Wt2 = (const float*)d_in[9];
  const float* bt2 = (const float*)d_in[10];
  const float* Wp = (const float*)d_in[11];
  const float* bp = (const float*)d_in[12];

  const int N = in_sizes[0] / IN_DIM;   // 8192
  const int E = in_sizes[1];            // 262144
  const int NC = N * HIDC;

  float* ws = (float*)d_ws;
  float* out_deg = ws;
  float* in_deg  = ws + N;
  float* src_nrm = ws + 2 * (size_t)N;
  float* dst_nrm = ws + 3 * (size_t)N;
  float* neg_sim = ws + 4 * (size_t)N;
  float* pos_sum = ws + 5 * (size_t)N;
  float* neg_sum = ws + 6 * (size_t)N;
  float* B0 = ws + 8 * (size_t)N;
  float* B1 = B0 + (size_t)NC;
  float* B2 = B1 + (size_t)NC;
  float* sim = B2 + (size_t)NC;
  unsigned short* zb = (unsigned short*)(sim + E);

  dim3 b256(256);
  dim3 gemm_block(16, 16);
  dim3 gemm_grid(N / 64, HIDC / 64);

  // degrees + norms
  hipMemsetAsync(out_deg, 0, 2 * (size_t)N * sizeof(float), stream);  // out_deg + in_deg
  deg_count_kernel<<<(E + 255) / 256, b256, 0, stream>>>(src, dst, out_deg, in_deg, E);
  make_norm_kernel<<<(N + 255) / 256, b256, 0, stream>>>(out_deg, in_deg, src_nrm, dst_nrm, N);

  // ---- online encoder: v ----
  gemm_f32<<<gemm_grid, gemm_block, 0, stream>>>(feat, W1, B0, N, IN_DIM);
  hipMemsetAsync(B1, 0, (size_t)NC * sizeof(float), stream);
  scatter_kernel<<<E, b256, 0, stream>>>(B0, src_nrm, src, dst, B1);
  post_agg_kernel<<<(NC + 255) / 256, b256, 0, stream>>>(B1, dst_nrm, b1, B2, NC, 1);  // B2 = h
  gemm_f32<<<gemm_grid, gemm_block, 0, stream>>>(B2, W2, B0, N, HIDC);
  hipMemsetAsync(B1, 0, (size_t)NC * sizeof(float), stream);
  scatter_kernel<<<E, b256, 0, stream>>>(B0, src_nrm, src, dst, B1);
  post_agg_kernel<<<(NC + 255) / 256, b256, 0, stream>>>(B1, dst_nrm, b2, B2, NC, 0);  // B2 = v

  // ---- target encoder: u ----
  gemm_f32<<<gemm_grid, gemm_block, 0, stream>>>(feat, Wt1, B0, N, IN_DIM);
  hipMemsetAsync(B1, 0, (size_t)NC * sizeof(float), stream);
  scatter_kernel<<<E, b256, 0, stream>>>(B0, src_nrm, src, dst, B1);
  post_agg_kernel<<<(NC + 255) / 256, b256, 0, stream>>>(B1, dst_nrm, bt1, B0, NC, 1); // B0 = hu
  gemm_f32<<<gemm_grid, gemm_block, 0, stream>>>(B0, Wt2, B1, N, HIDC);
  hipMemsetAsync(B0, 0, (size_t)NC * sizeof(float), stream);
  scatter_kernel<<<E, b256, 0, stream>>>(B1, src_nrm, src, dst, B0);
  post_agg_kernel<<<(NC + 255) / 256, b256, 0, stream>>>(B0, dst_nrm, bt2, B0, NC, 0); // B0 = u
  l2norm_kernel<<<N, b256, 0, stream>>>(B0, nullptr, B0);                              // B0 = un

  // ---- projector q, z ----
  gemm_f32<<<gemm_grid, gemm_block, 0, stream>>>(B2, Wp, B1, N, HIDC);
  l2norm_kernel<<<N, b256, 0, stream>>>(B1, bp, B1);       // B1 = q
  l2norm_kernel<<<N, b256, 0, stream>>>(B2, nullptr, B2);  // B2 = z

  // ---- neg_sim via bf16 MFMA ----
  to_bf16_kernel<<<(NC + 255) / 256, b256, 0, stream>>>(B2, zb, NC);
  hipMemsetAsync(neg_sim, 0, (size_t)N * sizeof(float), stream);
  const int JSPLIT = 8;
  dim3 ng(N / 64, JSPLIT);
  negsim_kernel<<<ng, b256, 0, stream>>>(zb, neg_sim, N / JSPLIT);

  // ---- edge scores ----
  edge_sim_kernel<<<(E + 3) / 4, b256, 0, stream>>>(B0, B1, src, dst, sim, E);
  hipMemsetAsync(pos_sum, 0, 2 * (size_t)N * sizeof(float), stream);  // pos_sum + neg_sum
  edge_scores_kernel<<<(E + 255) / 256, b256, 0, stream>>>(sim, dst, neg_sim, pos_sum, neg_sum, E);

  finalize_kernel<<<1, b256, 0, stream>>>(pos_sum, neg_sum, in_deg, (float*)d_out, N);
}

// Round 2
// 391.037 us; speedup vs baseline: 3.8909x; 3.8909x over previous
//
#include <hip/hip_runtime.h>

typedef unsigned short u16;
typedef unsigned int u32;
typedef __bf16 bf16x8 __attribute__((ext_vector_type(8)));
typedef float f32x4 __attribute__((ext_vector_type(4)));

#define HID 256
#define TEMP_INV 2.0f

__device__ __forceinline__ u16 f2b(float f) {
  union { float f; u32 u; } v; v.f = f;
  u32 u = v.u;
  u += 0x7FFFu + ((u >> 16) & 1u);
  return (u16)(u >> 16);
}
__device__ __forceinline__ float u2f(u32 u) { union { u32 u; float f; } v; v.u = u; return v.f; }

// ---------------- degree / norm ----------------
__global__ void deg_count_kernel(const int* __restrict__ src, const int* __restrict__ dst,
                                 float* __restrict__ out_deg, float* __restrict__ in_deg, int E) {
  int e = blockIdx.x * blockDim.x + threadIdx.x;
  if (e < E) {
    atomicAdd(&out_deg[src[e]], 1.0f);
    atomicAdd(&in_deg[dst[e]], 1.0f);
  }
}

__global__ void make_norm_kernel(const float* __restrict__ out_deg, const float* __restrict__ in_deg,
                                 float* __restrict__ src_norm, float* __restrict__ dst_norm, int N) {
  int n = blockIdx.x * blockDim.x + threadIdx.x;
  if (n < N) {
    float od = out_deg[n], id = in_deg[n];
    src_norm[n] = od > 0.f ? 1.0f / sqrtf(od) : 0.f;
    dst_norm[n] = id > 0.f ? 1.0f / sqrtf(id) : 0.f;
  }
}

// ---------------- CSR build ----------------
__global__ __launch_bounds__(256) void scan_offsets(const float* __restrict__ in_deg,
                                                    int* __restrict__ offs, int N) {
  __shared__ int sums[256];
  int t = threadIdx.x;
  int chunk = N / 256;
  int base = t * chunk;
  int loc = 0;
  for (int i = 0; i < chunk; ++i) loc += (int)in_deg[base + i];
  sums[t] = loc;
  __syncthreads();
  for (int d = 1; d < 256; d <<= 1) {
    int v = (t >= d) ? sums[t - d] : 0;
    __syncthreads();
    sums[t] += v;
    __syncthreads();
  }
  int run = (t == 0) ? 0 : sums[t - 1];
  for (int i = 0; i < chunk; ++i) {
    offs[base + i] = run;
    run += (int)in_deg[base + i];
  }
  if (t == 255) offs[N] = run;
}

__global__ void copy_cursor(const int* __restrict__ offs, int* __restrict__ cur, int N) {
  int i = blockIdx.x * 256 + threadIdx.x;
  if (i < N) cur[i] = offs[i];
}

__global__ void csr_fill(const int* __restrict__ src, const int* __restrict__ dst,
                         int* __restrict__ cur, int* __restrict__ csr_src, int E) {
  int e = blockIdx.x * 256 + threadIdx.x;
  if (e < E) {
    int pos = atomicAdd(&cur[dst[e]], 1);
    csr_src[pos] = src[e];
  }
}

// ---------------- conversions / weight packing ----------------
__global__ void cvt_f2b4(const float* __restrict__ in, u16* __restrict__ out, int count4) {
  int i = blockIdx.x * 256 + threadIdx.x;
  if (i < count4) {
    float4 v = ((const float4*)in)[i];
    ((u32*)out)[2 * i] = (u32)f2b(v.x) | ((u32)f2b(v.y) << 16);
    ((u32*)out)[2 * i + 1] = (u32)f2b(v.z) | ((u32)f2b(v.w) << 16);
  }
}

// vb[n][c] = bf16(vu[n][c]), c<256, vu row stride 512
__global__ void cvt_vb(const float* __restrict__ vu, u16* __restrict__ vb, int N) {
  int i = blockIdx.x * 256 + threadIdx.x;  // over N*64 float4s
  if (i < N * 64) {
    int n = i >> 6, c4 = i & 63;
    float4 v = *(const float4*)(vu + (size_t)n * 512 + c4 * 4);
    u32 lo = (u32)f2b(v.x) | ((u32)f2b(v.y) << 16);
    u32 hi = (u32)f2b(v.z) | ((u32)f2b(v.w) << 16);
    u32* p = (u32*)vb + ((size_t)n * 128 + c4 * 2);
    p[0] = lo; p[1] = hi;
  }
}

// w1T[n][k] (512x512): n<256 -> W1[k][n], else Wt1[k][n-256]
__global__ void build_w1T(const float* __restrict__ W1, const float* __restrict__ Wt1,
                          u16* __restrict__ out) {
  int idx = blockIdx.x * 256 + threadIdx.x;  // 512*512
  int n = idx >> 9, k = idx & 511;
  float v = (n < 256) ? W1[(size_t)k * 256 + n] : Wt1[(size_t)k * 256 + (n - 256)];
  out[idx] = f2b(v);
}

// w2T[n][k] (512x512): blockdiag(W2^T, Wt2^T)
__global__ void build_w2T(const float* __restrict__ W2, const float* __restrict__ Wt2,
                          u16* __restrict__ out) {
  int idx = blockIdx.x * 256 + threadIdx.x;
  int n = idx >> 9, k = idx & 511;
  float v = 0.f;
  if (n < 256) { if (k < 256) v = W2[(size_t)k * 256 + n]; }
  else { if (k >= 256) v = Wt2[(size_t)(k - 256) * 256 + (n - 256)]; }
  out[idx] = f2b(v);
}

__global__ void build_wpT(const float* __restrict__ Wp, u16* __restrict__ out) {
  int idx = blockIdx.x * 256 + threadIdx.x;  // 256*256
  int n = idx >> 8, k = idx & 255;
  out[idx] = f2b(Wp[(size_t)k * 256 + n]);
}

// ---------------- bf16 MFMA GEMM: C[M,Nn] = A[M,K] @ BT[Nn,K]^T ----------------
// MODE 0: bf16 C out; MODE 1: f32 C out; MODE 2: negsim partial rowsum of exp(2*C)
template <int MODE>
__global__ __launch_bounds__(256) void gemm_bf16(const u16* __restrict__ A,
                                                 const u16* __restrict__ BT,
                                                 void* __restrict__ outp,
                                                 float* __restrict__ partial,
                                                 int M, int Nn, int K) {
  __shared__ u16 As[128][40];
  __shared__ u16 Bs[128][40];
  const int t = threadIdx.x;
  const int lane = t & 63, wave = t >> 6;
  const int wm = wave >> 1, wn = wave & 1;
  const size_t m0 = (size_t)blockIdx.x * 128, n0 = (size_t)blockIdx.y * 128;
  const int r16 = lane & 15, kg = lane >> 4;

  f32x4 acc[4][4];
#pragma unroll
  for (int i = 0; i < 4; ++i)
#pragma unroll
    for (int j = 0; j < 4; ++j) acc[i][j] = (f32x4){0.f, 0.f, 0.f, 0.f};

  for (int k0 = 0; k0 < K; k0 += 32) {
#pragma unroll
    for (int i = 0; i < 2; ++i) {
      int ch = t + i * 256;          // 512 chunks of 8 bf16
      int m = ch >> 2, kc = ch & 3;
      *(bf16x8*)&As[m][kc * 8] = *(const bf16x8*)(A + (m0 + m) * (size_t)K + k0 + kc * 8);
      *(bf16x8*)&Bs[m][kc * 8] = *(const bf16x8*)(BT + (n0 + m) * (size_t)K + k0 + kc * 8);
    }
    __syncthreads();
    bf16x8 af[4], bfv[4];
#pragma unroll
    for (int mi = 0; mi < 4; ++mi) af[mi] = *(const bf16x8*)&As[wm * 64 + mi * 16 + r16][kg * 8];
#pragma unroll
    for (int ni = 0; ni < 4; ++ni) bfv[ni] = *(const bf16x8*)&Bs[wn * 64 + ni * 16 + r16][kg * 8];
#pragma unroll
    for (int mi = 0; mi < 4; ++mi)
#pragma unroll
      for (int ni = 0; ni < 4; ++ni)
        acc[mi][ni] = __builtin_amdgcn_mfma_f32_16x16x32_bf16(af[mi], bfv[ni], acc[mi][ni], 0, 0, 0);
    __syncthreads();
  }

  if (MODE == 2) {
    // rowsum of exp(2*acc) over this block's 128 cols
    float rowv[4][4];
#pragma unroll
    for (int mi = 0; mi < 4; ++mi)
#pragma unroll
      for (int rr = 0; rr < 4; ++rr) {
        float s = 0.f;
#pragma unroll
        for (int ni = 0; ni < 4; ++ni) s += __expf(acc[mi][ni][rr] * TEMP_INV);
#pragma unroll
        for (int msk = 1; msk < 16; msk <<= 1) s += __shfl_xor(s, msk, 64);
        rowv[mi][rr] = s;
      }
    float* red = (float*)&As[0][0];
    if (r16 == 0) {
#pragma unroll
      for (int mi = 0; mi < 4; ++mi)
#pragma unroll
        for (int rr = 0; rr < 4; ++rr)
          red[wn * 128 + wm * 64 + mi * 16 + kg * 4 + rr] = rowv[mi][rr];
    }
    __syncthreads();
    if (t < 128) partial[(size_t)blockIdx.y * M + m0 + t] = red[t] + red[128 + t];
  } else {
#pragma unroll
    for (int mi = 0; mi < 4; ++mi)
#pragma unroll
      for (int rr = 0; rr < 4; ++rr) {
        size_t row = m0 + wm * 64 + mi * 16 + kg * 4 + rr;
#pragma unroll
        for (int ni = 0; ni < 4; ++ni) {
          size_t col = n0 + wn * 64 + ni * 16 + r16;
          if (MODE == 0)
            ((u16*)outp)[row * Nn + col] = f2b(acc[mi][ni][rr]);
          else
            ((float*)outp)[row * Nn + col] = acc[mi][ni][rr];
        }
      }
  }
}

// ---------------- CSR gather-aggregate + epilogue (512 channels = v|u fused) ----------------
template <bool RELU>
__global__ __launch_bounds__(256) void agg_csr(const u16* __restrict__ xw,
                                               const int* __restrict__ csr_src,
                                               const int* __restrict__ offs,
                                               const float* __restrict__ src_norm,
                                               const float* __restrict__ dst_norm,
                                               const float* __restrict__ bias_v,
                                               const float* __restrict__ bias_u,
                                               u16* __restrict__ out_b,
                                               float* __restrict__ out_f) {
  const int n = blockIdx.x, t = threadIdx.x;
  const int beg = offs[n], end = offs[n + 1];
  float a0 = 0.f, a1 = 0.f;
  int i = beg;
  for (; i + 2 <= end; i += 2) {
    int s0 = csr_src[i], s1 = csr_src[i + 1];
    float w0 = src_norm[s0], w1 = src_norm[s1];
    u32 p0 = *(const u32*)(xw + (size_t)s0 * 512 + t * 2);
    u32 p1 = *(const u32*)(xw + (size_t)s1 * 512 + t * 2);
    a0 += w0 * u2f(p0 << 16);
    a1 += w0 * u2f(p0 & 0xFFFF0000u);
    a0 += w1 * u2f(p1 << 16);
    a1 += w1 * u2f(p1 & 0xFFFF0000u);
  }
  if (i < end) {
    int s0 = csr_src[i];
    float w0 = src_norm[s0];
    u32 p0 = *(const u32*)(xw + (size_t)s0 * 512 + t * 2);
    a0 += w0 * u2f(p0 << 16);
    a1 += w0 * u2f(p0 & 0xFFFF0000u);
  }
  float dn = dst_norm[n];
  const float* bb = (t < 128) ? bias_v : bias_u;
  int cc = (2 * t) & 255;
  float v0 = dn * a0 + bb[cc], v1 = dn * a1 + bb[cc + 1];
  if (RELU) { v0 = fmaxf(v0, 0.f); v1 = fmaxf(v1, 0.f); }
  if (out_b) ((u32*)out_b)[(size_t)n * 256 + t] = (u32)f2b(v0) | ((u32)f2b(v1) << 16);
  if (out_f) *(float2*)(out_f + (size_t)n * 512 + 2 * t) = make_float2(v0, v1);
}

// ---------------- l2-normalize one 256-ch row (fp32 in, bf16 out) ----------------
__global__ __launch_bounds__(256) void l2norm_b(const float* __restrict__ in, int ld,
                                                const float* __restrict__ bias,
                                                u16* __restrict__ out) {
  int n = blockIdx.x, c = threadIdx.x;
  float v = in[(size_t)n * ld + c] + (bias ? bias[c] : 0.f);
  float s = v * v;
#pragma unroll
  for (int m = 1; m < 64; m <<= 1) s += __shfl_xor(s, m, 64);
  __shared__ float red[4];
  if ((c & 63) == 0) red[c >> 6] = s;
  __syncthreads();
  float tot = red[0] + red[1] + red[2] + red[3];
  out[(size_t)n * HID + c] = f2b(v / fmaxf(sqrtf(tot), 1e-12f));
}

// ---------------- neg_sim = sum over 64 partials ----------------
__global__ void negsim_reduce(const float* __restrict__ partial, float* __restrict__ neg_sim,
                              int N, int nj) {
  int n = blockIdx.x * 256 + threadIdx.x;
  if (n < N) {
    float s = 0.f;
    for (int j = 0; j < nj; ++j) s += partial[(size_t)j * N + n];
    neg_sim[n] = s;
  }
}

// ---------------- fused edge scores: sim + pos/neg scatter ----------------
__global__ __launch_bounds__(256) void edge_fused(const u16* __restrict__ un,
                                                  const u16* __restrict__ q,
                                                  const int* __restrict__ src,
                                                  const int* __restrict__ dst,
                                                  const float* __restrict__ neg_sim,
                                                  float* __restrict__ pos_sum,
                                                  float* __restrict__ neg_sum, int E) {
  int e = blockIdx.x * 4 + (threadIdx.x >> 6);
  if (e >= E) return;
  int lane = threadIdx.x & 63;
  int s = src[e], d = dst[e];
  const u32* pa = (const u32*)(un + (size_t)s * HID) + lane * 2;
  const u32* pb = (const u32*)(q + (size_t)d * HID) + lane * 2;
  u32 a0 = pa[0], a1 = pa[1], b0 = pb[0], b1 = pb[1];
  float dot = u2f(a0 << 16) * u2f(b0 << 16) + u2f(a0 & 0xFFFF0000u) * u2f(b0 & 0xFFFF0000u) +
              u2f(a1 << 16) * u2f(b1 << 16) + u2f(a1 & 0xFFFF0000u) * u2f(b1 & 0xFFFF0000u);
#pragma unroll
  for (int m = 1; m < 64; m <<= 1) dot += __shfl_xor(dot, m, 64);
  if (lane == 0) {
    float sim = dot * TEMP_INV;
    atomicAdd(&pos_sum[d], sim);
    atomicAdd(&neg_sum[d], __logf(neg_sim[d] + __expf(sim)));
  }
}

// ---------------- final mean ----------------
__global__ __launch_bounds__(256) void finalize_kernel(const float* __restrict__ pos_sum,
                                                       const float* __restrict__ neg_sum,
                                                       const float* __restrict__ in_deg,
                                                       float* __restrict__ out, int N) {
  float acc = 0.f;
  for (int n = threadIdx.x; n < N; n += 256) {
    float d = in_deg[n];
    if (d > 0.f) acc += (neg_sum[n] - pos_sum[n]) / fmaxf(d, 1.0f);
  }
#pragma unroll
  for (int m = 1; m < 64; m <<= 1) acc += __shfl_xor(acc, m, 64);
  __shared__ float red[4];
  if ((threadIdx.x & 63) == 0) red[threadIdx.x >> 6] = acc;
  __syncthreads();
  if (threadIdx.x == 0) out[0] = (red[0] + red[1] + red[2] + red[3]) / (float)N;
}

extern "C" void kernel_launch(void* const* d_in, const int* in_sizes, int n_in,
                              void* d_out, int out_size, void* d_ws, size_t ws_size,
                              hipStream_t stream) {
  const float* feat = (const float*)d_in[0];
  const int* src = (const int*)d_in[1];
  const int* dst = (const int*)d_in[2];
  const float* W1 = (const float*)d_in[3];
  const float* b1 = (const float*)d_in[4];
  const float* W2 = (const float*)d_in[5];
  const float* b2 = (const float*)d_in[6];
  const float* Wt1 = (const float*)d_in[7];
  const float* bt1 = (const float*)d_in[8];
  const float* Wt2 = (const float*)d_in[9];
  const float* bt2 = (const float*)d_in[10];
  const float* Wp = (const float*)d_in[11];
  const float* bp = (const float*)d_in[12];

  const int N = in_sizes[0] / 512;  // 8192
  const int E = in_sizes[1];        // 262144
  const int NJB = N / 128;          // 64 j-blocks for negsim

  char* w = (char*)d_ws;
  size_t off = 0;
  auto alloc = [&](size_t bytes) -> void* {
    void* p = w + off;
    off = (off + bytes + 255) & ~(size_t)255;
    return p;
  };

  float* out_deg = (float*)alloc((size_t)N * 4);
  float* in_deg = (float*)alloc((size_t)N * 4);
  float* src_nrm = (float*)alloc((size_t)N * 4);
  float* dst_nrm = (float*)alloc((size_t)N * 4);
  float* neg_sim = (float*)alloc((size_t)N * 4);
  float* pos_sum = (float*)alloc((size_t)N * 4);
  float* neg_sum = (float*)alloc((size_t)N * 4);
  int* offs = (int*)alloc((size_t)(N + 1) * 4);
  int* cursor = (int*)alloc((size_t)N * 4);
  int* csr_src = (int*)alloc((size_t)E * 4);
  u16* w1T = (u16*)alloc(512 * 512 * 2);
  u16* w2T = (u16*)alloc(512 * 512 * 2);
  u16* wpT = (u16*)alloc(256 * 256 * 2);
  u16* featb = (u16*)alloc((size_t)N * 512 * 2);  // later: q_pre (f32 N*256)
  u16* XWb = (u16*)alloc((size_t)N * 512 * 2);    // later: zb | unb
  u16* hb = (u16*)alloc((size_t)N * 512 * 2);     // later: vb | qb
  float* vu = (float*)alloc((size_t)N * 512 * 4);
  float* partial = (float*)alloc((size_t)NJB * N * 4);

  float* q_pre = (float*)featb;
  u16* zb = XWb;
  u16* unb = XWb + (size_t)N * 256;
  u16* vb = hb;
  u16* qb = hb + (size_t)N * 256;

  dim3 b256(256);

  // degrees, norms, CSR
  hipMemsetAsync(out_deg, 0, 2 * (size_t)N * 4, stream);
  deg_count_kernel<<<(E + 255) / 256, b256, 0, stream>>>(src, dst, out_deg, in_deg, E);
  make_norm_kernel<<<(N + 255) / 256, b256, 0, stream>>>(out_deg, in_deg, src_nrm, dst_nrm, N);
  scan_offsets<<<1, b256, 0, stream>>>(in_deg, offs, N);
  copy_cursor<<<(N + 255) / 256, b256, 0, stream>>>(offs, cursor, N);
  csr_fill<<<(E + 255) / 256, b256, 0, stream>>>(src, dst, cursor, csr_src, E);

  // pack inputs/weights to bf16
  cvt_f2b4<<<(N * 128 + 255) / 256, b256, 0, stream>>>(feat, featb, N * 128);
  build_w1T<<<(512 * 512) / 256, b256, 0, stream>>>(W1, Wt1, w1T);
  build_w2T<<<(512 * 512) / 256, b256, 0, stream>>>(W2, Wt2, w2T);
  build_wpT<<<(256 * 256) / 256, b256, 0, stream>>>(Wp, wpT);

  // layer 1 (online+target fused): XW = feat @ [W1|Wt1]; h = relu(dn*agg + b)
  gemm_bf16<0><<<dim3(N / 128, 4), b256, 0, stream>>>(featb, w1T, XWb, nullptr, N, 512, 512);
  agg_csr<true><<<N, b256, 0, stream>>>(XWb, csr_src, offs, src_nrm, dst_nrm, b1, bt1, hb, nullptr);

  // layer 2: XW2 = h @ blockdiag(W2,Wt2); vu = dn*agg + b
  gemm_bf16<0><<<dim3(N / 128, 4), b256, 0, stream>>>(hb, w2T, XWb, nullptr, N, 512, 512);
  agg_csr<false><<<N, b256, 0, stream>>>(XWb, csr_src, offs, src_nrm, dst_nrm, b2, bt2, nullptr, vu);

  // z, un, projector q
  cvt_vb<<<(N * 64 + 255) / 256, b256, 0, stream>>>(vu, vb, N);
  l2norm_b<<<N, b256, 0, stream>>>(vu, 512, nullptr, zb);
  l2norm_b<<<N, b256, 0, stream>>>(vu + 256, 512, nullptr, unb);
  gemm_bf16<1><<<dim3(N / 128, 2), b256, 0, stream>>>(vb, wpT, q_pre, nullptr, N, 256, 256);
  l2norm_b<<<N, b256, 0, stream>>>(q_pre, 256, bp, qb);

  // neg_sim = rowsum exp(2 * z z^T) via MFMA GEMM with epilogue
  gemm_bf16<2><<<dim3(N / 128, NJB), b256, 0, stream>>>(zb, zb, nullptr, partial, N, N, 256);
  negsim_reduce<<<(N + 255) / 256, b256, 0, stream>>>(partial, neg_sim, N, NJB);

  // edge scores + segment sums
  hipMemsetAsync(pos_sum, 0, 2 * (size_t)N * 4, stream);
  edge_fused<<<(E + 3) / 4, b256, 0, stream>>>(unb, qb, src, dst, neg_sim, pos_sum, neg_sum, E);

  finalize_kernel<<<1, b256, 0, stream>>>(pos_sum, neg_sum, in_deg, (float*)d_out, N);
}

// Round 3
// 390.273 us; speedup vs baseline: 3.8985x; 1.0020x over previous
//
#include <hip/hip_runtime.h>

typedef unsigned short u16;
typedef unsigned int u32;
typedef __bf16 bf16x8 __attribute__((ext_vector_type(8)));
typedef float f32x4 __attribute__((ext_vector_type(4)));

#define HID 256
#define TEMP_INV 2.0f

__device__ __forceinline__ u16 f2b(float f) {
  union { float f; u32 u; } v; v.f = f;
  u32 u = v.u;
  u += 0x7FFFu + ((u >> 16) & 1u);
  return (u16)(u >> 16);
}
__device__ __forceinline__ float u2f(u32 u) { union { u32 u; float f; } v; v.u = u; return v.f; }

// ---------------- degree / norm ----------------
__global__ void deg_count_kernel(const int* __restrict__ src, const int* __restrict__ dst,
                                 float* __restrict__ out_deg, float* __restrict__ in_deg, int E) {
  int e = blockIdx.x * blockDim.x + threadIdx.x;
  if (e < E) {
    atomicAdd(&out_deg[src[e]], 1.0f);
    atomicAdd(&in_deg[dst[e]], 1.0f);
  }
}

__global__ void make_norm_kernel(const float* __restrict__ out_deg, const float* __restrict__ in_deg,
                                 float* __restrict__ src_norm, float* __restrict__ dst_norm, int N) {
  int n = blockIdx.x * blockDim.x + threadIdx.x;
  if (n < N) {
    float od = out_deg[n], id = in_deg[n];
    src_norm[n] = od > 0.f ? 1.0f / sqrtf(od) : 0.f;
    dst_norm[n] = id > 0.f ? 1.0f / sqrtf(id) : 0.f;
  }
}

// ---------------- CSR build ----------------
__global__ __launch_bounds__(256) void scan_offsets(const float* __restrict__ in_deg,
                                                    int* __restrict__ offs, int N) {
  __shared__ int sums[256];
  int t = threadIdx.x;
  int chunk = N / 256;
  int base = t * chunk;
  int loc = 0;
  for (int i = 0; i < chunk; ++i) loc += (int)in_deg[base + i];
  sums[t] = loc;
  __syncthreads();
  for (int d = 1; d < 256; d <<= 1) {
    int v = (t >= d) ? sums[t - d] : 0;
    __syncthreads();
    sums[t] += v;
    __syncthreads();
  }
  int run = (t == 0) ? 0 : sums[t - 1];
  for (int i = 0; i < chunk; ++i) {
    offs[base + i] = run;
    run += (int)in_deg[base + i];
  }
  if (t == 255) offs[N] = run;
}

__global__ void copy_cursor(const int* __restrict__ offs, int* __restrict__ cur, int N) {
  int i = blockIdx.x * 256 + threadIdx.x;
  if (i < N) cur[i] = offs[i];
}

__global__ void csr_fill(const int* __restrict__ src, const int* __restrict__ dst,
                         int* __restrict__ cur, int* __restrict__ csr_src, int E) {
  int e = blockIdx.x * 256 + threadIdx.x;
  if (e < E) {
    int pos = atomicAdd(&cur[dst[e]], 1);
    csr_src[pos] = src[e];
  }
}

// ---------------- conversions / weight packing ----------------
__global__ void cvt_f2b4(const float* __restrict__ in, u16* __restrict__ out, int count4) {
  int i = blockIdx.x * 256 + threadIdx.x;
  if (i < count4) {
    float4 v = ((const float4*)in)[i];
    ((u32*)out)[2 * i] = (u32)f2b(v.x) | ((u32)f2b(v.y) << 16);
    ((u32*)out)[2 * i + 1] = (u32)f2b(v.z) | ((u32)f2b(v.w) << 16);
  }
}

// vb[n][c] = bf16(vu[n][c]), c<256, vu row stride 512
__global__ void cvt_vb(const float* __restrict__ vu, u16* __restrict__ vb, int N) {
  int i = blockIdx.x * 256 + threadIdx.x;  // over N*64 float4s
  if (i < N * 64) {
    int n = i >> 6, c4 = i & 63;
    float4 v = *(const float4*)(vu + (size_t)n * 512 + c4 * 4);
    u32 lo = (u32)f2b(v.x) | ((u32)f2b(v.y) << 16);
    u32 hi = (u32)f2b(v.z) | ((u32)f2b(v.w) << 16);
    u32* p = (u32*)vb + ((size_t)n * 128 + c4 * 2);
    p[0] = lo; p[1] = hi;
  }
}

// w1T[n][k] (512x512): n<256 -> W1[k][n], else Wt1[k][n-256]
__global__ void build_w1T(const float* __restrict__ W1, const float* __restrict__ Wt1,
                          u16* __restrict__ out) {
  int idx = blockIdx.x * 256 + threadIdx.x;  // 512*512
  int n = idx >> 9, k = idx & 511;
  float v = (n < 256) ? W1[(size_t)k * 256 + n] : Wt1[(size_t)k * 256 + (n - 256)];
  out[idx] = f2b(v);
}

// w2T[n][k] (512x512): blockdiag(W2^T, Wt2^T)
__global__ void build_w2T(const float* __restrict__ W2, const float* __restrict__ Wt2,
                          u16* __restrict__ out) {
  int idx = blockIdx.x * 256 + threadIdx.x;
  int n = idx >> 9, k = idx & 511;
  float v = 0.f;
  if (n < 256) { if (k < 256) v = W2[(size_t)k * 256 + n]; }
  else { if (k >= 256) v = Wt2[(size_t)(k - 256) * 256 + (n - 256)]; }
  out[idx] = f2b(v);
}

__global__ void build_wpT(const float* __restrict__ Wp, u16* __restrict__ out) {
  int idx = blockIdx.x * 256 + threadIdx.x;  // 256*256
  int n = idx >> 8, k = idx & 255;
  out[idx] = f2b(Wp[(size_t)k * 256 + n]);
}

// ---------------- bf16 MFMA GEMM: C[M,Nn] = A[M,K] @ BT[Nn,K]^T ----------------
// MODE 0: bf16 C out; MODE 1: f32 C out; MODE 2: negsim partial rowsum of exp(2*C)
template <int MODE>
__global__ __launch_bounds__(256) void gemm_bf16(const u16* __restrict__ A,
                                                 const u16* __restrict__ BT,
                                                 void* __restrict__ outp,
                                                 float* __restrict__ partial,
                                                 int M, int Nn, int K) {
  __shared__ u16 As[128][40];
  __shared__ u16 Bs[128][40];
  const int t = threadIdx.x;
  const int lane = t & 63, wave = t >> 6;
  const int wm = wave >> 1, wn = wave & 1;
  const size_t m0 = (size_t)blockIdx.x * 128, n0 = (size_t)blockIdx.y * 128;
  const int r16 = lane & 15, kg = lane >> 4;

  f32x4 acc[4][4];
#pragma unroll
  for (int i = 0; i < 4; ++i)
#pragma unroll
    for (int j = 0; j < 4; ++j) acc[i][j] = (f32x4){0.f, 0.f, 0.f, 0.f};

  for (int k0 = 0; k0 < K; k0 += 32) {
#pragma unroll
    for (int i = 0; i < 2; ++i) {
      int ch = t + i * 256;          // 512 chunks of 8 bf16
      int m = ch >> 2, kc = ch & 3;
      *(bf16x8*)&As[m][kc * 8] = *(const bf16x8*)(A + (m0 + m) * (size_t)K + k0 + kc * 8);
      *(bf16x8*)&Bs[m][kc * 8] = *(const bf16x8*)(BT + (n0 + m) * (size_t)K + k0 + kc * 8);
    }
    __syncthreads();
    bf16x8 af[4], bfv[4];
#pragma unroll
    for (int mi = 0; mi < 4; ++mi) af[mi] = *(const bf16x8*)&As[wm * 64 + mi * 16 + r16][kg * 8];
#pragma unroll
    for (int ni = 0; ni < 4; ++ni) bfv[ni] = *(const bf16x8*)&Bs[wn * 64 + ni * 16 + r16][kg * 8];
#pragma unroll
    for (int mi = 0; mi < 4; ++mi)
#pragma unroll
      for (int ni = 0; ni < 4; ++ni)
        acc[mi][ni] = __builtin_amdgcn_mfma_f32_16x16x32_bf16(af[mi], bfv[ni], acc[mi][ni], 0, 0, 0);
    __syncthreads();
  }

  if (MODE == 2) {
    // rowsum of exp(2*acc) over this block's 128 cols
    float rowv[4][4];
#pragma unroll
    for (int mi = 0; mi < 4; ++mi)
#pragma unroll
      for (int rr = 0; rr < 4; ++rr) {
        float s = 0.f;
#pragma unroll
        for (int ni = 0; ni < 4; ++ni) s += __expf(acc[mi][ni][rr] * TEMP_INV);
#pragma unroll
        for (int msk = 1; msk < 16; msk <<= 1) s += __shfl_xor(s, msk, 64);
        rowv[mi][rr] = s;
      }
    float* red = (float*)&As[0][0];
    if (r16 == 0) {
#pragma unroll
      for (int mi = 0; mi < 4; ++mi)
#pragma unroll
        for (int rr = 0; rr < 4; ++rr)
          red[wn * 128 + wm * 64 + mi * 16 + kg * 4 + rr] = rowv[mi][rr];
    }
    __syncthreads();
    if (t < 128) partial[(size_t)blockIdx.y * M + m0 + t] = red[t] + red[128 + t];
  } else {
#pragma unroll
    for (int mi = 0; mi < 4; ++mi)
#pragma unroll
      for (int rr = 0; rr < 4; ++rr) {
        size_t row = m0 + wm * 64 + mi * 16 + kg * 4 + rr;
#pragma unroll
        for (int ni = 0; ni < 4; ++ni) {
          size_t col = n0 + wn * 64 + ni * 16 + r16;
          if (MODE == 0)
            ((u16*)outp)[row * Nn + col] = f2b(acc[mi][ni][rr]);
          else
            ((float*)outp)[row * Nn + col] = acc[mi][ni][rr];
        }
      }
  }
}

// ---------------- CSR gather-aggregate + epilogue (512 channels = v|u fused) ----------------
template <bool RELU>
__global__ __launch_bounds__(256) void agg_csr(const u16* __restrict__ xw,
                                               const int* __restrict__ csr_src,
                                               const int* __restrict__ offs,
                                               const float* __restrict__ src_norm,
                                               const float* __restrict__ dst_norm,
                                               const float* __restrict__ bias_v,
                                               const float* __restrict__ bias_u,
                                               u16* __restrict__ out_b,
                                               float* __restrict__ out_f) {
  const int n = blockIdx.x, t = threadIdx.x;
  const int beg = offs[n], end = offs[n + 1];
  float a0 = 0.f, a1 = 0.f;
  int i = beg;
  for (; i + 2 <= end; i += 2) {
    int s0 = csr_src[i], s1 = csr_src[i + 1];
    float w0 = src_norm[s0], w1 = src_norm[s1];
    u32 p0 = *(const u32*)(xw + (size_t)s0 * 512 + t * 2);
    u32 p1 = *(const u32*)(xw + (size_t)s1 * 512 + t * 2);
    a0 += w0 * u2f(p0 << 16);
    a1 += w0 * u2f(p0 & 0xFFFF0000u);
    a0 += w1 * u2f(p1 << 16);
    a1 += w1 * u2f(p1 & 0xFFFF0000u);
  }
  if (i < end) {
    int s0 = csr_src[i];
    float w0 = src_norm[s0];
    u32 p0 = *(const u32*)(xw + (size_t)s0 * 512 + t * 2);
    a0 += w0 * u2f(p0 << 16);
    a1 += w0 * u2f(p0 & 0xFFFF0000u);
  }
  float dn = dst_norm[n];
  const float* bb = (t < 128) ? bias_v : bias_u;
  int cc = (2 * t) & 255;
  float v0 = dn * a0 + bb[cc], v1 = dn * a1 + bb[cc + 1];
  if (RELU) { v0 = fmaxf(v0, 0.f); v1 = fmaxf(v1, 0.f); }
  if (out_b) ((u32*)out_b)[(size_t)n * 256 + t] = (u32)f2b(v0) | ((u32)f2b(v1) << 16);
  if (out_f) *(float2*)(out_f + (size_t)n * 512 + 2 * t) = make_float2(v0, v1);
}

// ---------------- l2-normalize one 256-ch row (fp32 in, bf16 out) ----------------
__global__ __launch_bounds__(256) void l2norm_b(const float* __restrict__ in, int ld,
                                                const float* __restrict__ bias,
                                                u16* __restrict__ out) {
  int n = blockIdx.x, c = threadIdx.x;
  float v = in[(size_t)n * ld + c] + (bias ? bias[c] : 0.f);
  float s = v * v;
#pragma unroll
  for (int m = 1; m < 64; m <<= 1) s += __shfl_xor(s, m, 64);
  __shared__ float red[4];
  if ((c & 63) == 0) red[c >> 6] = s;
  __syncthreads();
  float tot = red[0] + red[1] + red[2] + red[3];
  out[(size_t)n * HID + c] = f2b(v / fmaxf(sqrtf(tot), 1e-12f));
}

// ---------------- neg_sim = sum over 64 partials ----------------
__global__ void negsim_reduce(const float* __restrict__ partial, float* __restrict__ neg_sim,
                              int N, int nj) {
  int n = blockIdx.x * 256 + threadIdx.x;
  if (n < N) {
    float s = 0.f;
    for (int j = 0; j < nj; ++j) s += partial[(size_t)j * N + n];
    neg_sim[n] = s;
  }
}

// ---------------- fused edge scores: sim + pos/neg scatter ----------------
__global__ __launch_bounds__(256) void edge_fused(const u16* __restrict__ un,
                                                  const u16* __restrict__ q,
                                                  const int* __restrict__ src,
                                                  const int* __restrict__ dst,
                                                  const float* __restrict__ neg_sim,
                                                  float* __restrict__ pos_sum,
                                                  float* __restrict__ neg_sum, int E) {
  int e = blockIdx.x * 4 + (threadIdx.x >> 6);
  if (e >= E) return;
  int lane = threadIdx.x & 63;
  int s = src[e], d = dst[e];
  const u32* pa = (const u32*)(un + (size_t)s * HID) + lane * 2;
  const u32* pb = (const u32*)(q + (size_t)d * HID) + lane * 2;
  u32 a0 = pa[0], a1 = pa[1], b0 = pb[0], b1 = pb[1];
  float dot = u2f(a0 << 16) * u2f(b0 << 16) + u2f(a0 & 0xFFFF0000u) * u2f(b0 & 0xFFFF0000u) +
              u2f(a1 << 16) * u2f(b1 << 16) + u2f(a1 & 0xFFFF0000u) * u2f(b1 & 0xFFFF0000u);
#pragma unroll
  for (int m = 1; m < 64; m <<= 1) dot += __shfl_xor(dot, m, 64);
  if (lane == 0) {
    float sim = dot * TEMP_INV;
    atomicAdd(&pos_sum[d], sim);
    atomicAdd(&neg_sum[d], __logf(neg_sim[d] + __expf(sim)));
  }
}

// ---------------- final mean ----------------
__global__ __launch_bounds__(256) void finalize_kernel(const float* __restrict__ pos_sum,
                                                       const float* __restrict__ neg_sum,
                                                       const float* __restrict__ in_deg,
                                                       float* __restrict__ out, int N) {
  float acc = 0.f;
  for (int n = threadIdx.x; n < N; n += 256) {
    float d = in_deg[n];
    if (d > 0.f) acc += (neg_sum[n] - pos_sum[n]) / fmaxf(d, 1.0f);
  }
#pragma unroll
  for (int m = 1; m < 64; m <<= 1) acc += __shfl_xor(acc, m, 64);
  __shared__ float red[4];
  if ((threadIdx.x & 63) == 0) red[threadIdx.x >> 6] = acc;
  __syncthreads();
  if (threadIdx.x == 0) out[0] = (red[0] + red[1] + red[2] + red[3]) / (float)N;
}

extern "C" void kernel_launch(void* const* d_in, const int* in_sizes, int n_in,
                              void* d_out, int out_size, void* d_ws, size_t ws_size,
                              hipStream_t stream) {
  const float* feat = (const float*)d_in[0];
  const int* src = (const int*)d_in[1];
  const int* dst = (const int*)d_in[2];
  const float* W1 = (const float*)d_in[3];
  const float* b1 = (const float*)d_in[4];
  const float* W2 = (const float*)d_in[5];
  const float* b2 = (const float*)d_in[6];
  const float* Wt1 = (const float*)d_in[7];
  const float* bt1 = (const float*)d_in[8];
  const float* Wt2 = (const float*)d_in[9];
  const float* bt2 = (const float*)d_in[10];
  const float* Wp = (const float*)d_in[11];
  const float* bp = (const float*)d_in[12];

  const int N = in_sizes[0] / 512;  // 8192
  const int E = in_sizes[1];        // 262144
  const int NJB = N / 128;          // 64 j-blocks for negsim

  char* w = (char*)d_ws;
  size_t off = 0;
  auto alloc = [&](size_t bytes) -> void* {
    void* p = w + off;
    off = (off + bytes + 255) & ~(size_t)255;
    return p;
  };

  float* out_deg = (float*)alloc((size_t)N * 4);
  float* in_deg = (float*)alloc((size_t)N * 4);
  float* src_nrm = (float*)alloc((size_t)N * 4);
  float* dst_nrm = (float*)alloc((size_t)N * 4);
  float* neg_sim = (float*)alloc((size_t)N * 4);
  float* pos_sum = (float*)alloc((size_t)N * 4);
  float* neg_sum = (float*)alloc((size_t)N * 4);
  int* offs = (int*)alloc((size_t)(N + 1) * 4);
  int* cursor = (int*)alloc((size_t)N * 4);
  int* csr_src = (int*)alloc((size_t)E * 4);
  u16* w1T = (u16*)alloc(512 * 512 * 2);
  u16* w2T = (u16*)alloc(512 * 512 * 2);
  u16* wpT = (u16*)alloc(256 * 256 * 2);
  u16* featb = (u16*)alloc((size_t)N * 512 * 2);  // later: q_pre (f32 N*256)
  u16* XWb = (u16*)alloc((size_t)N * 512 * 2);    // later: zb | unb
  u16* hb = (u16*)alloc((size_t)N * 512 * 2);     // later: vb | qb
  float* vu = (float*)alloc((size_t)N * 512 * 4);
  float* partial = (float*)alloc((size_t)NJB * N * 4);

  float* q_pre = (float*)featb;
  u16* zb = XWb;
  u16* unb = XWb + (size_t)N * 256;
  u16* vb = hb;
  u16* qb = hb + (size_t)N * 256;

  dim3 b256(256);

  // degrees, norms, CSR
  hipMemsetAsync(out_deg, 0, 2 * (size_t)N * 4, stream);
  deg_count_kernel<<<(E + 255) / 256, b256, 0, stream>>>(src, dst, out_deg, in_deg, E);
  make_norm_kernel<<<(N + 255) / 256, b256, 0, stream>>>(out_deg, in_deg, src_nrm, dst_nrm, N);
  scan_offsets<<<1, b256, 0, stream>>>(in_deg, offs, N);
  copy_cursor<<<(N + 255) / 256, b256, 0, stream>>>(offs, cursor, N);
  csr_fill<<<(E + 255) / 256, b256, 0, stream>>>(src, dst, cursor, csr_src, E);

  // pack inputs/weights to bf16
  cvt_f2b4<<<(N * 128 + 255) / 256, b256, 0, stream>>>(feat, featb, N * 128);
  build_w1T<<<(512 * 512) / 256, b256, 0, stream>>>(W1, Wt1, w1T);
  build_w2T<<<(512 * 512) / 256, b256, 0, stream>>>(W2, Wt2, w2T);
  build_wpT<<<(256 * 256) / 256, b256, 0, stream>>>(Wp, wpT);

  // layer 1 (online+target fused): XW = feat @ [W1|Wt1]; h = relu(dn*agg + b)
  gemm_bf16<0><<<dim3(N / 128, 4), b256, 0, stream>>>(featb, w1T, XWb, nullptr, N, 512, 512);
  agg_csr<true><<<N, b256, 0, stream>>>(XWb, csr_src, offs, src_nrm, dst_nrm, b1, bt1, hb, nullptr);

  // layer 2: XW2 = h @ blockdiag(W2,Wt2); vu = dn*agg + b
  gemm_bf16<0><<<dim3(N / 128, 4), b256, 0, stream>>>(hb, w2T, XWb, nullptr, N, 512, 512);
  agg_csr<false><<<N, b256, 0, stream>>>(XWb, csr_src, offs, src_nrm, dst_nrm, b2, bt2, nullptr, vu);

  // z, un, projector q
  cvt_vb<<<(N * 64 + 255) / 256, b256, 0, stream>>>(vu, vb, N);
  l2norm_b<<<N, b256, 0, stream>>>(vu, 512, nullptr, zb);
  l2norm_b<<<N, b256, 0, stream>>>(vu + 256, 512, nullptr, unb);
  gemm_bf16<1><<<dim3(N / 128, 2), b256, 0, stream>>>(vb, wpT, q_pre, nullptr, N, 256, 256);
  l2norm_b<<<N, b256, 0, stream>>>(q_pre, 256, bp, qb);

  // neg_sim = rowsum exp(2 * z z^T) via MFMA GEMM with epilogue
  gemm_bf16<2><<<dim3(N / 128, NJB), b256, 0, stream>>>(zb, zb, nullptr, partial, N, N, 256);
  negsim_reduce<<<(N + 255) / 256, b256, 0, stream>>>(partial, neg_sim, N, NJB);

  // edge scores + segment sums
  hipMemsetAsync(pos_sum, 0, 2 * (size_t)N * 4, stream);
  edge_fused<<<(E + 3) / 4, b256, 0, stream>>>(unb, qb, src, dst, neg_sim, pos_sum, neg_sum, E);

  finalize_kernel<<<1, b256, 0, stream>>>(pos_sum, neg_sum, in_deg, (float*)d_out, N);
}